// Round 17
// baseline (98.873 us; speedup 1.0000x reference)
//
#include <hip/hip_runtime.h>
#include <cstdint>
#include <cstddef>

typedef __attribute__((ext_vector_type(8))) short short8;   // 8 bf16 (MFMA A/B frag)
typedef __attribute__((ext_vector_type(4))) float f32x4;    // MFMA C/D frag
typedef __attribute__((ext_vector_type(4))) unsigned int u32x4;

#define NROT 24
#define COUT 8
#define CIN  4
#define M_TOT 192        // 24*8
#define PLANE 262144     // 64^3
#define XD 3
#define XH 6
#define XW 66

__device__ __forceinline__ unsigned short f2bf(float f) {
  unsigned u = __builtin_bit_cast(unsigned, f);
  return (unsigned short)((u + 0x7FFFu + ((u >> 16) & 1u)) >> 16);  // RNE
}

__device__ __forceinline__ void rot_mat(int r, int Rm[3][3]) {
  // exactly the reference enumeration: perms lexicographic x signs [1,-1]^3, det>0
  const int perms[6][3] = {{0,1,2},{0,2,1},{1,0,2},{1,2,0},{2,0,1},{2,1,0}};
  const int psign[6] = {1,-1,-1,1,1,-1};
  int count = 0;
  for (int pe = 0; pe < 6; ++pe)
    for (int si = 0; si < 8; ++si) {
      const int s0 = (si & 4) ? -1 : 1;
      const int s1 = (si & 2) ? -1 : 1;
      const int s2 = (si & 1) ? -1 : 1;
      if (psign[pe] * s0 * s1 * s2 > 0) {
        if (count == r) {
          for (int a = 0; a < 3; ++a)
            for (int b = 0; b < 3; ++b) Rm[a][b] = 0;
          Rm[0][perms[pe][0]] = s0;
          Rm[1][perms[pe][1]] = s1;
          Rm[2][perms[pe][2]] = s2;
          return;
        }
        ++count;
      }
    }
}

// ---- pre-kernel: build W_rot in MFMA fragment layout, bf16 (12 blocks, 1 ent/thread) ----
__global__ void prep_A(const float* __restrict__ weight, unsigned short* __restrict__ Abuf) {
  const int ent = blockIdx.x * 256 + threadIdx.x;
  if (ent >= 12 * 4 * 64) return;
  const int lane = ent & 63;
  const int mc = ent >> 6;
  const int Mtile = mc >> 2, chunk = mc & 3;
  const int m = Mtile * 16 + (lane & 15);
  const int r = m >> 3, o = m & 7;
  int Rm[3][3];
  rot_mat(r, Rm);
  unsigned short v8[8];
#pragma unroll
  for (int e = 0; e < 8; ++e) {
    const int k = chunk * 32 + (lane >> 4) * 8 + e;
    unsigned short hv = 0;
    if (k < 108) {
      const int t = k >> 2, i = k & 3;
      const int kd = t / 9, kh = (t / 3) % 3, kw = t % 3;
      const int cx = kw - 1, cy = kh - 1, cz = kd - 1;
      const int g0 = Rm[0][0] * cx + Rm[0][1] * cy + Rm[0][2] * cz;
      const int g1 = Rm[1][0] * cx + Rm[1][1] * cy + Rm[1][2] * cz;
      const int g2 = Rm[2][0] * cx + Rm[2][1] * cy + Rm[2][2] * cz;
      const int sd = g2 + 1, sh = g1 + 1, sw = g0 + 1;
      hv = f2bf(weight[(o * CIN + i) * 27 + sd * 9 + sh * 3 + sw]);
    }
    v8[e] = hv;
  }
  u32x4 packed;
  packed.x = (unsigned)v8[0] | ((unsigned)v8[1] << 16);
  packed.y = (unsigned)v8[2] | ((unsigned)v8[3] << 16);
  packed.z = (unsigned)v8[4] | ((unsigned)v8[5] << 16);
  packed.w = (unsigned)v8[6] | ((unsigned)v8[7] << 16);
  ((u32x4*)Abuf)[ent] = packed;
}

// ---- main kernel: implicit-GEMM conv, swapped MFMA operands, DIRECT stores ----
// R12 structure minus the LDS bounce: store each acc[q] immediately (f32x4/lane,
// 16 channels x 64B segments per wave-instr). Removes 48 wave-local drains + obuf
// (LDS 13.6->9.3 KB, VGPR down) — isolates whether the bounce was still earning.
__global__ __launch_bounds__(256)
void conv_mfma(const float* __restrict__ xin,
               const unsigned short* __restrict__ Abuf,
               const float* __restrict__ bias,
               float* __restrict__ out) {
  __shared__ uint2 xsv[XD * XH * XW];    // 9.3 KB input tile (channels-last bf16)

  const int tid = threadIdx.x;
  int bid = blockIdx.x;
  const int ht = bid & 15; bid >>= 4;
  const int d  = bid & 63; bid >>= 6;
  const int n  = bid;            // 0..1
  const int h0 = ht * 4;

  // ---- stage x tile (zero halo), f32 -> bf16, channels-last ----
  const float* xb = xin + (size_t)n * CIN * PLANE;
  for (int v = tid; v < XD * XH * XW; v += 256) {
    const int ww = v % XW;
    const int rest = v / XW;
    const int yy = rest % XH;
    const int zz = rest / XH;
    const int gz = d - 1 + zz, gy = h0 - 1 + yy, gw = ww - 1;
    unsigned p0 = 0, p1 = 0;
    if ((unsigned)gz < 64u && (unsigned)gy < 64u && (unsigned)gw < 64u) {
      const int base = gz * 4096 + gy * 64 + gw;
      const unsigned a0 = f2bf(xb[base]);
      const unsigned a1 = f2bf(xb[base + PLANE]);
      const unsigned a2 = f2bf(xb[base + 2 * PLANE]);
      const unsigned a3 = f2bf(xb[base + 3 * PLANE]);
      p0 = a0 | (a1 << 16);
      p1 = a2 | (a3 << 16);
    }
    xsv[v] = make_uint2(p0, p1);
  }

  const int wv = tid >> 6;
  const int lane = tid & 63;
  const int lg = lane >> 4;      // lane-group 0..3
  const int col = lane & 15;

  // swapped layout: channel = col (lane&15)  ->  one bias value per lane
  const float bv = bias[col & 7];

  // ---- precompute B(x)-read voxel offsets (uint2 units) per chunk/half ----
  int voff[4][2];
#pragma unroll
  for (int c = 0; c < 4; ++c)
#pragma unroll
    for (int hf = 0; hf < 2; ++hf) {
      int t = c * 8 + lg * 2 + hf;
      t = t > 26 ? 26 : t;              // clamp pad region to real data (W=0 there)
      const int kd = t / 9, kh = (t / 3) % 3, kw = t % 3;
      voff[c][hf] = (kd * XH + kh) * XW + col + kw;
    }

  __syncthreads();

  const int nbase = n * M_TOT;
  const int wv3 = wv * 3;
  const short8* Ab8 = (const short8*)Abuf;
  const int spb = d * 4096 + h0 * 64;    // block's spatial base

#pragma unroll 1
  for (int j = 0; j < 3; ++j) {
    // W-fragments for this channel-tile (Abuf is tiny & L2-hot)
    short8 af[4];
#pragma unroll
    for (int c = 0; c < 4; ++c)
      af[c] = Ab8[((wv3 + j) * 4 + c) * 64 + lane];

    // lane's output channel plane for this j
    float* op = out + (size_t)(nbase + (wv3 + j) * 16 + col) * PLANE + spb + lg * 4;

#pragma unroll 1
    for (int hh = 0; hh < 4; ++hh) {
#pragma unroll
      for (int q = 0; q < 4; ++q) {
        const int dl = hh * XW + q * 16;
        f32x4 a = {bv, bv, bv, bv};
#pragma unroll
        for (int c = 0; c < 4; ++c) {
          const uint2 lo = xsv[voff[c][0] + dl];
          const uint2 hi = xsv[voff[c][1] + dl];
          u32x4 bw;
          bw.x = lo.x; bw.y = lo.y; bw.z = hi.x; bw.w = hi.y;
          const short8 b = __builtin_bit_cast(short8, bw);
          a = __builtin_amdgcn_mfma_f32_16x16x32_bf16(b, af[c], a, 0, 0, 0);
        }
        // direct store: channel col, h = h0+hh, w = q*16 + lg*4 + reg
        *(f32x4*)(op + hh * 64 + q * 16) = a;
      }
    }
  }
}

extern "C" void kernel_launch(void* const* d_in, const int* in_sizes, int n_in,
                              void* d_out, int out_size, void* d_ws, size_t ws_size,
                              hipStream_t stream) {
  const float* x = (const float*)d_in[0];
  const float* w = (const float*)d_in[1];
  const float* b = (const float*)d_in[2];
  float* out = (float*)d_out;
  unsigned short* Abuf = (unsigned short*)d_ws;  // needs 12*4*64*16 = 49152 B

  prep_A<<<dim3(12), dim3(256), 0, stream>>>(w, Abuf);
  // grid: 16 h-tiles * 64 d * 2 n = 2048 blocks
  conv_mfma<<<dim3(2048), dim3(256), 0, stream>>>(x, Abuf, b, out);
}

// Round 18
// 90.113 us; speedup vs baseline: 1.0972x; 1.0972x over previous
//
#include <hip/hip_runtime.h>
#include <cstdint>
#include <cstddef>

typedef __attribute__((ext_vector_type(8))) short short8;   // 8 bf16 (MFMA A/B frag)
typedef __attribute__((ext_vector_type(4))) float f32x4;    // MFMA C/D frag
typedef __attribute__((ext_vector_type(4))) unsigned int u32x4;

#define NROT 24
#define COUT 8
#define CIN  4
#define M_TOT 192        // 24*8
#define PLANE 262144     // 64^3
#define XD 3
#define XH 6
#define XW 66

__device__ __forceinline__ unsigned short f2bf(float f) {
  unsigned u = __builtin_bit_cast(unsigned, f);
  return (unsigned short)((u + 0x7FFFu + ((u >> 16) & 1u)) >> 16);  // RNE
}

__device__ __forceinline__ void rot_mat(int r, int Rm[3][3]) {
  // exactly the reference enumeration: perms lexicographic x signs [1,-1]^3, det>0
  const int perms[6][3] = {{0,1,2},{0,2,1},{1,0,2},{1,2,0},{2,0,1},{2,1,0}};
  const int psign[6] = {1,-1,-1,1,1,-1};
  int count = 0;
  for (int pe = 0; pe < 6; ++pe)
    for (int si = 0; si < 8; ++si) {
      const int s0 = (si & 4) ? -1 : 1;
      const int s1 = (si & 2) ? -1 : 1;
      const int s2 = (si & 1) ? -1 : 1;
      if (psign[pe] * s0 * s1 * s2 > 0) {
        if (count == r) {
          for (int a = 0; a < 3; ++a)
            for (int b = 0; b < 3; ++b) Rm[a][b] = 0;
          Rm[0][perms[pe][0]] = s0;
          Rm[1][perms[pe][1]] = s1;
          Rm[2][perms[pe][2]] = s2;
          return;
        }
        ++count;
      }
    }
}

// ---- pre-kernel: build W_rot in MFMA fragment layout, bf16 (12 blocks, 1 ent/thread) ----
__global__ void prep_A(const float* __restrict__ weight, unsigned short* __restrict__ Abuf) {
  const int ent = blockIdx.x * 256 + threadIdx.x;
  if (ent >= 12 * 4 * 64) return;
  const int lane = ent & 63;
  const int mc = ent >> 6;
  const int Mtile = mc >> 2, chunk = mc & 3;
  const int m = Mtile * 16 + (lane & 15);
  const int r = m >> 3, o = m & 7;
  int Rm[3][3];
  rot_mat(r, Rm);
  unsigned short v8[8];
#pragma unroll
  for (int e = 0; e < 8; ++e) {
    const int k = chunk * 32 + (lane >> 4) * 8 + e;
    unsigned short hv = 0;
    if (k < 108) {
      const int t = k >> 2, i = k & 3;
      const int kd = t / 9, kh = (t / 3) % 3, kw = t % 3;
      const int cx = kw - 1, cy = kh - 1, cz = kd - 1;
      const int g0 = Rm[0][0] * cx + Rm[0][1] * cy + Rm[0][2] * cz;
      const int g1 = Rm[1][0] * cx + Rm[1][1] * cy + Rm[1][2] * cz;
      const int g2 = Rm[2][0] * cx + Rm[2][1] * cy + Rm[2][2] * cz;
      const int sd = g2 + 1, sh = g1 + 1, sw = g0 + 1;
      hv = f2bf(weight[(o * CIN + i) * 27 + sd * 9 + sh * 3 + sw]);
    }
    v8[e] = hv;
  }
  u32x4 packed;
  packed.x = (unsigned)v8[0] | ((unsigned)v8[1] << 16);
  packed.y = (unsigned)v8[2] | ((unsigned)v8[3] << 16);
  packed.z = (unsigned)v8[4] | ((unsigned)v8[5] << 16);
  packed.w = (unsigned)v8[6] | ((unsigned)v8[7] << 16);
  ((u32x4*)Abuf)[ent] = packed;
}

// ---- main kernel: implicit-GEMM conv, swapped MFMA operands, per-hh epilogue ----
// R12 configuration — measured optimum of the contiguity/occupancy tradeoff:
// LDS bounce to 256B-contiguous channel-major bursts, acc4 + tiny obuf (4.3KB),
// linear blockIdx, plain stores. (A/B'd against: 64B direct -10%, 512B/1KB bursts
// -8/-19%, XCD swizzle -7%, nt stores -3%, forced 8 blk/CU -226% via spills.)
__global__ __launch_bounds__(256)
void conv_mfma(const float* __restrict__ xin,
               const unsigned short* __restrict__ Abuf,
               const float* __restrict__ bias,
               float* __restrict__ out) {
  __shared__ uint2 xsv[XD * XH * XW];    // 9.3 KB input tile (channels-last bf16)
  __shared__ float obuf[4][4][68];       // [wv][ch&3][w pad 68] = 4.3 KB

  const int tid = threadIdx.x;
  int bid = blockIdx.x;
  const int ht = bid & 15; bid >>= 4;
  const int d  = bid & 63; bid >>= 6;
  const int n  = bid;            // 0..1
  const int h0 = ht * 4;

  // ---- stage x tile (zero halo), f32 -> bf16, channels-last ----
  const float* xb = xin + (size_t)n * CIN * PLANE;
  for (int v = tid; v < XD * XH * XW; v += 256) {
    const int ww = v % XW;
    const int rest = v / XW;
    const int yy = rest % XH;
    const int zz = rest / XH;
    const int gz = d - 1 + zz, gy = h0 - 1 + yy, gw = ww - 1;
    unsigned p0 = 0, p1 = 0;
    if ((unsigned)gz < 64u && (unsigned)gy < 64u && (unsigned)gw < 64u) {
      const int base = gz * 4096 + gy * 64 + gw;
      const unsigned a0 = f2bf(xb[base]);
      const unsigned a1 = f2bf(xb[base + PLANE]);
      const unsigned a2 = f2bf(xb[base + 2 * PLANE]);
      const unsigned a3 = f2bf(xb[base + 3 * PLANE]);
      p0 = a0 | (a1 << 16);
      p1 = a2 | (a3 << 16);
    }
    xsv[v] = make_uint2(p0, p1);
  }

  const int wv = tid >> 6;
  const int lane = tid & 63;
  const int lg = lane >> 4;      // lane-group 0..3
  const int col = lane & 15;

  // swapped layout: channel = col (lane&15)  ->  one bias value per lane
  const float bv = bias[col & 7];

  // ---- precompute B(x)-read voxel offsets (uint2 units) per chunk/half ----
  int voff[4][2];
#pragma unroll
  for (int c = 0; c < 4; ++c)
#pragma unroll
    for (int hf = 0; hf < 2; ++hf) {
      int t = c * 8 + lg * 2 + hf;
      t = t > 26 ? 26 : t;              // clamp pad region to real data (W=0 there)
      const int kd = t / 9, kh = (t / 3) % 3, kw = t % 3;
      voff[c][hf] = (kd * XH + kh) * XW + col + kw;
    }

  __syncthreads();

  const int nbase = n * M_TOT;
  const int wv3 = wv * 3;
  const short8* Ab8 = (const short8*)Abuf;
  const int spb = d * 4096 + h0 * 64;    // block's spatial base
  const int cc = lane >> 4;              // reader channel-sub
  const int off = (lane & 15) * 4;       // reader w offset

#pragma unroll 1
  for (int j = 0; j < 3; ++j) {
    // W-fragments for this channel-tile (Abuf is tiny & L2-hot)
    short8 af[4];
#pragma unroll
    for (int c = 0; c < 4; ++c)
      af[c] = Ab8[((wv3 + j) * 4 + c) * 64 + lane];

    const size_t jch = (size_t)(nbase + (wv3 + j) * 16);

#pragma unroll 1
    for (int hh = 0; hh < 4; ++hh) {
      // ---- compute one h-row: 4 n-tiles ----
      f32x4 acc[4];
#pragma unroll
      for (int q = 0; q < 4; ++q) {
        const int dl = hh * XW + q * 16;
        f32x4 a = {bv, bv, bv, bv};
#pragma unroll
        for (int c = 0; c < 4; ++c) {
          const uint2 lo = xsv[voff[c][0] + dl];
          const uint2 hi = xsv[voff[c][1] + dl];
          u32x4 bw;
          bw.x = lo.x; bw.y = lo.y; bw.z = hi.x; bw.w = hi.y;
          const short8 b = __builtin_bit_cast(short8, bw);
          a = __builtin_amdgcn_mfma_f32_16x16x32_bf16(b, af[c], a, 0, 0, 0);
        }
        acc[q] = a;
      }

      // ---- per-hh bounce: 4 g-phases, each 4 channels x 256B contiguous ----
      // acc[q][reg]: channel col, h = h0+hh, w = q*16 + lg*4 + reg
#pragma unroll
      for (int g = 0; g < 4; ++g) {
        if ((col >> 2) == g) {
#pragma unroll
          for (int q = 0; q < 4; ++q)
            *(f32x4*)&obuf[wv][col & 3][q * 16 + lg * 4] = acc[q];
        }
        // RAW drain (wave-local LDS ops are processed in order; WAR to next g's
        // writes is safe same-wave after this drain + sched pin)
        __builtin_amdgcn_sched_barrier(0);
        asm volatile("s_waitcnt lgkmcnt(0)" ::: "memory");
        __builtin_amdgcn_sched_barrier(0);
        const f32x4 v = *(const f32x4*)&obuf[wv][cc][off];
        float* p = out + (jch + g * 4 + cc) * PLANE + spb + hh * 64 + off;
        *(f32x4*)p = v;
        __builtin_amdgcn_sched_barrier(0);
      }
    }
  }
}

extern "C" void kernel_launch(void* const* d_in, const int* in_sizes, int n_in,
                              void* d_out, int out_size, void* d_ws, size_t ws_size,
                              hipStream_t stream) {
  const float* x = (const float*)d_in[0];
  const float* w = (const float*)d_in[1];
  const float* b = (const float*)d_in[2];
  float* out = (float*)d_out;
  unsigned short* Abuf = (unsigned short*)d_ws;  // needs 12*4*64*16 = 49152 B

  prep_A<<<dim3(12), dim3(256), 0, stream>>>(w, Abuf);
  // grid: 16 h-tiles * 64 d * 2 n = 2048 blocks
  conv_mfma<<<dim3(2048), dim3(256), 0, stream>>>(x, Abuf, b, out);
}